// Round 4
// baseline (1189.453 us; speedup 1.0000x reference)
//
#include <hip/hip_runtime.h>

// MON forward-backward splitting via Anderson acceleration, MI355X/gfx950.
// R3: persistent single kernel with hand-rolled grid barrier (no cooperative API,
//     whose 64KB-sharedMem occupancy precheck killed R2). 256 blocks x 1024 thr,
//     VGPR<=128 + LDS 61.6KB => capacity 2 blocks/CU => all-resident guaranteed.
//     Unified element mapping: z stays in registers FX->conv; Fh/G block-local.

typedef unsigned short u16;
using short8 = __attribute__((ext_vector_type(8))) short;
using f32x4  = __attribute__((ext_vector_type(4))) float;

#define SLOT 4194304              // elements per history slot (32768 px * 128 ch)
#define NBLK 256

__device__ __forceinline__ u16 f2bf(float f) {
  unsigned u = __builtin_bit_cast(unsigned, f);
  unsigned r = (u + 0x7FFFu + ((u >> 16) & 1u)) >> 16;   // RNE, finite inputs
  return (u16)r;
}
__device__ __forceinline__ float bf2f(u16 h) {
  unsigned u = ((unsigned)h) << 16;
  return __builtin_bit_cast(float, u);
}
__device__ __forceinline__ void gl_lds16(const void* g, void* l) {
  __builtin_amdgcn_global_load_lds(
      (const __attribute__((address_space(1))) unsigned int*)g,
      (__attribute__((address_space(3))) unsigned int*)l, 16, 0, 0);
}

// grid barrier: sense via monotonically increasing generation counter.
__device__ __forceinline__ void gsync(unsigned* cnt, unsigned* gen) {
  __syncthreads();
  if (threadIdx.x == 0) {
    __threadfence();                              // release my writes
    unsigned g = atomicAdd(gen, 0u);              // read current generation
    if (atomicAdd(cnt, 1u) == NBLK - 1u) {        // last arriver
      atomicExch(cnt, 0u);                        // reset BEFORE bumping gen
      __threadfence();
      atomicAdd(gen, 1u);
    } else {
      while (atomicAdd(gen, 0u) == g) __builtin_amdgcn_s_sleep(1);
    }
    __threadfence();                              // acquire others' writes
  }
  __syncthreads();
}

// ---------------- W[cout][cin][ky][kx] f32 -> Wb[o][cout][cin] bf16; zero barrier state
__global__ void __launch_bounds__(256) k_prepw(const float* __restrict__ W, u16* __restrict__ Wb,
                                               unsigned* cnt, unsigned* gen) {
  if (blockIdx.x == 0 && threadIdx.x == 0) { cnt[0] = 0u; gen[0] = 0u; }
  int t = blockIdx.x * 256 + threadIdx.x;       // 9*128*128 threads
  int o = t >> 14;
  int rem = t & 16383;
  int cout = rem >> 7, cin = rem & 127;
  float v = W[(size_t)cout * 1152 + (size_t)cin * 9 + o];
  Wb[(size_t)o * 16384 + (size_t)cout * 128 + cin] = f2bf(v);
}

// ---------------- x NCHW f32 -> zm bf16 swizzled NHWC: mask ? x : 1/128
// masked entries never change afterwards; unmasked rewritten every FX.
__global__ void __launch_bounds__(256) k_prepx(const float* __restrict__ x,
    const int* __restrict__ mask_, u16* __restrict__ zm0) {
  int t = blockIdx.x * 256 + threadIdx.x;       // 524288 threads
  int g = t >> 15, p = t & 32767;
  int nb = p >> 10, gp = p & 1023, px = p & 31;
  int mk = mask_[p];
  const u16 ubf = 0x3C00;                       // bf16(1/128) exact
  short8 zv;
#pragma unroll
  for (int u = 0; u < 8; ++u) {
    float v = x[(size_t)nb * 131072 + (size_t)(g * 8 + u) * 1024 + gp];
    zv[u] = (short)(mk ? f2bf(v) : ubf);
  }
  size_t off = (size_t)p * 128 + (size_t)((g ^ (px & 7)) << 3);
  *(short8*)(zm0 + off) = zv;
}

// ---------------- the whole Anderson loop, persistent ----------------
// 256 blocks x 1024 threads; block = 4 rows (128 px) of one image; 8 blocks/image.
// Wave (wr=wid>>3, wc=wid&7): 64-px half x 16 channels. Thread owns channel colc
// for 16 pixels (identical mapping in FX and conv epilogue => z in registers).
__global__ void __launch_bounds__(1024, 4) k_loop(
    u16* __restrict__ zm, const int* __restrict__ mask_,
    const u16* __restrict__ Wb, const float* __restrict__ bias,
    float* __restrict__ Fh, u16* __restrict__ G_all,
    float* __restrict__ gpart, float* __restrict__ resp,
    float* __restrict__ out, unsigned* cnt, unsigned* gen)
{
  __shared__ char smem[61600];
  char*  As       = smem;                        // 6 rows * 34 cols * 256B = 52224
  float* rowmax_s = (float*)(smem + 52224);      // 128 px * 8 = 4096B
  float* rowsum_s = (float*)(smem + 56320);      // 4096B
  float* red      = (float*)(smem + 60416);      // 16 waves * 8 = 512B
  float* gram_s   = (float*)(smem + 60928);      // 25
  float* alpha_s  = (float*)(smem + 61056);      // 5
  float* res_s    = (float*)(smem + 61080);      // 1
  int*   mk_s     = (int*)(smem + 61088);        // 128

  const int tid = threadIdx.x;
  const int wid = tid >> 6, lane = tid & 63;
  const int lhi = lane >> 4, llo = lane & 15;
  const int wr = wid >> 3, wc = wid & 7;
  const int bid = blockIdx.x;
  const int n = bid >> 3, y0 = (bid & 7) << 2;
  const int pixbase = (n << 10) + (y0 << 5);
  const int colc = (wc << 4) + llo;
  const float bc = bias[colc];

  if (tid < 128) mk_s[tid] = mask_[pixbase + tid];
  if (tid < 25) gram_s[tid] = 0.f;

  f32x4 zv[4];
  f32x4 acc[4];
  for (int e = 0; e < 50; ++e) {
    const int slot = e % 5;
    const int nact = e < 5 ? e : 5;
    // ================= FX: z = sum_j alpha_j Fh_j (registers); zm for unmasked ====
    if (e == 0) {
      const f32x4 cz = {0.0078125f, 0.0078125f, 0.0078125f, 0.0078125f};
      zv[0] = cz; zv[1] = cz; zv[2] = cz; zv[3] = cz;
      // zm already holds z0-masked from k_prepx
    } else {
      if (e == 1) {
        if (tid < 5) alpha_s[tid] = (tid == 0) ? 1.f : 0.f;
      } else if (tid == 0) {                     // bordered 6x6 solve, f32 GE w/ pivot
        float A[6][7];
        for (int i = 0; i < 5; ++i)
          for (int j = 0; j < 5; ++j)
            A[i + 1][j + 1] = (i < nact && j < nact)
                ? gram_s[i * 5 + j] + ((i == j) ? 1e-4f : 0.f)
                : ((i == j) ? 1.f : 0.f);
        A[0][0] = 0.f;
        for (int j = 0; j < 5; ++j) { float aj = (j < nact) ? 1.f : 0.f; A[0][j + 1] = aj; A[j + 1][0] = aj; }
        A[0][6] = 1.f;
        for (int i = 1; i < 6; ++i) A[i][6] = 0.f;
        for (int c = 0; c < 6; ++c) {
          int p = c; float mx = fabsf(A[c][c]);
          for (int r = c + 1; r < 6; ++r) { float v = fabsf(A[r][c]); if (v > mx) { mx = v; p = r; } }
          if (p != c) for (int q = c; q < 7; ++q) { float tmp = A[c][q]; A[c][q] = A[p][q]; A[p][q] = tmp; }
          float piv = A[c][c];
          for (int r = c + 1; r < 6; ++r) {
            float fr = A[r][c] / piv;
            for (int q = c; q < 7; ++q) A[r][q] -= fr * A[c][q];
          }
        }
        float sol[6];
        for (int r = 5; r >= 0; --r) {
          float s = A[r][6];
          for (int q = r + 1; q < 6; ++q) s -= A[r][q] * sol[q];
          sol[r] = s / A[r][r];
        }
        for (int j = 0; j < 5; ++j) alpha_s[j] = sol[j + 1];
      }
      __syncthreads();
      const float a0 = alpha_s[0], a1 = alpha_s[1], a2 = alpha_s[2],
                  a3 = alpha_s[3], a4 = alpha_s[4];
#pragma unroll
      for (int m2 = 0; m2 < 4; ++m2)
#pragma unroll
        for (int rr = 0; rr < 4; ++rr) {
          int p = (wr << 6) + (m2 << 4) + (lhi << 2) + rr;
          int gp = pixbase + p;
          size_t base = (size_t)gp * 128 + colc;
          float z = a0 * Fh[base];
          if (nact > 1) z += a1 * Fh[(size_t)SLOT + base];
          if (nact > 2) z += a2 * Fh[2 * (size_t)SLOT + base];
          if (nact > 3) z += a3 * Fh[3 * (size_t)SLOT + base];
          if (nact > 4) z += a4 * Fh[4 * (size_t)SLOT + base];
          zv[m2][rr] = z;
          if (!mk_s[p]) {
            int pos = (((colc >> 3) ^ (gp & 7)) << 3) | (colc & 7);   // gp&7 == x&7
            zm[(size_t)gp * 128 + pos] = f2bf(z);
          }
        }
    }
    gsync(cnt, gen);
    // ================= CONV: stage 6 halo'd rows; 144 MFMAs/wave ================
#pragma unroll
    for (int r2 = 0; r2 < 3; ++r2) {
      int r = (r2 << 1) + (tid >> 9);
      int y = y0 - 1 + r;
      int t5 = tid & 511;
      if ((unsigned)y < 32u) {
        const char* src = (const char*)zm + ((size_t)((n << 10) + (y << 5)) << 8);
        gl_lds16(src + t5 * 16, As + r * 8704 + 256 + ((t5 & ~63) << 4));
      } else {
        f32x4 zz = {0.f, 0.f, 0.f, 0.f};
        *(f32x4*)(As + r * 8704 + 256 + (t5 << 4)) = zz;
      }
    }
    if (tid < 192) {                             // zero pads: cols 0 and 33, 6 rows
      int r = tid >> 5, cc = tid & 31;
      int col = (cc < 16) ? 0 : 33, gc = cc & 15;
      f32x4 zz = {0.f, 0.f, 0.f, 0.f};
      *(f32x4*)(As + r * 8704 + (col << 8) + (gc << 4)) = zz;
    }
    __syncthreads();

    const f32x4 z4 = {0.f, 0.f, 0.f, 0.f};
    acc[0] = z4; acc[1] = z4; acc[2] = z4; acc[3] = z4;
#pragma unroll
    for (int o = 0; o < 9; ++o) {
      const int dy = o / 3, dx = o % 3;
      short8 bfr[4];
#pragma unroll
      for (int kk = 0; kk < 4; ++kk)
        bfr[kk] = *(const short8*)(Wb + o * 16384 + colc * 128 + ((kk << 2) + lhi) * 8);
#pragma unroll
      for (int kk = 0; kk < 4; ++kk) {
        const int kg = (kk << 2) + lhi;
#pragma unroll
        for (int m2 = 0; m2 < 4; ++m2) {
          int p = (wr << 6) + (m2 << 4) + llo;
          int r = (p >> 5) + dy, cl = (p & 31) + dx;
          int sg = kg ^ ((cl - 1) & 7);
          short8 af = *(const short8*)(As + r * 8704 + (cl << 8) + (sg << 4));
          acc[m2] = __builtin_amdgcn_mfma_f32_16x16x32_bf16(af, bfr[kk], acc[m2], 0, 0, 0);
        }
      }
    }

    // ===== epilogue: damp, channel-softmax(128), fnew, G, gram/res partials =====
#pragma unroll
    for (int m2 = 0; m2 < 4; ++m2)
#pragma unroll
      for (int rr = 0; rr < 4; ++rr)
        acc[m2][rr] = 0.1f * zv[m2][rr] + 0.9f * (acc[m2][rr] + bc);
#pragma unroll
    for (int m2 = 0; m2 < 4; ++m2)
#pragma unroll
      for (int rr = 0; rr < 4; ++rr) {
        float v = acc[m2][rr];
        v = fmaxf(v, __shfl_xor(v, 1)); v = fmaxf(v, __shfl_xor(v, 2));
        v = fmaxf(v, __shfl_xor(v, 4)); v = fmaxf(v, __shfl_xor(v, 8));
        if (llo == 0) rowmax_s[((wr << 6) + (m2 << 4) + (lhi << 2) + rr) * 8 + wc] = v;
      }
    __syncthreads();
#pragma unroll
    for (int m2 = 0; m2 < 4; ++m2)
#pragma unroll
      for (int rr = 0; rr < 4; ++rr) {
        int p = (wr << 6) + (m2 << 4) + (lhi << 2) + rr;
        f32x4 m0 = *(const f32x4*)&rowmax_s[p * 8];
        f32x4 m1 = *(const f32x4*)&rowmax_s[p * 8 + 4];
        float M = fmaxf(fmaxf(fmaxf(m0[0], m0[1]), fmaxf(m0[2], m0[3])),
                        fmaxf(fmaxf(m1[0], m1[1]), fmaxf(m1[2], m1[3])));
        float ev = __expf(acc[m2][rr] - M);
        acc[m2][rr] = ev;
        float s = ev;
        s += __shfl_xor(s, 1); s += __shfl_xor(s, 2);
        s += __shfl_xor(s, 4); s += __shfl_xor(s, 8);
        if (llo == 0) rowsum_s[p * 8 + wc] = s;
      }
    __syncthreads();

    float sd = 0.f, sf = 0.f;
    float gd16[16];
#pragma unroll
    for (int m2 = 0; m2 < 4; ++m2)
#pragma unroll
      for (int rr = 0; rr < 4; ++rr) {
        int p = (wr << 6) + (m2 << 4) + (lhi << 2) + rr;
        f32x4 s0 = *(const f32x4*)&rowsum_s[p * 8];
        f32x4 s1 = *(const f32x4*)&rowsum_s[p * 8 + 4];
        float S = s0[0] + s0[1] + s0[2] + s0[3] + s1[0] + s1[1] + s1[2] + s1[3];
        float fnew = acc[m2][rr] * (1.0f / S);
        acc[m2][rr] = fnew;                      // keep: output at break
        Fh[(size_t)slot * SLOT + (size_t)(pixbase + p) * 128 + colc] = fnew;
        float gd = fnew - zv[m2][rr];
        gd16[m2 * 4 + rr] = gd;
        sd += gd * gd; sf += fnew * fnew;
      }
    {
      short8 h0, h1;
#pragma unroll
      for (int i = 0; i < 8; ++i) { h0[i] = (short)f2bf(gd16[i]); h1[i] = (short)f2bf(gd16[8 + i]); }
      size_t gb = (size_t)bid * 16384 + (size_t)tid * 16;
      u16* Gs = G_all + (size_t)slot * SLOT;
      *(short8*)(Gs + gb) = h0;
      *(short8*)(Gs + gb + 8) = h1;
      const int jmax = e < 4 ? e : 4;
      float gacc[5];
#pragma unroll
      for (int j = 0; j < 5; ++j) {
        if (j > jmax) { gacc[j] = 0.f; continue; }
        if (j == slot) {
          float a = 0.f;
#pragma unroll
          for (int i = 0; i < 16; ++i) a += gd16[i] * gd16[i];
          gacc[j] = a;
        } else {
          short8 q0 = *(const short8*)(G_all + (size_t)j * SLOT + gb);
          short8 q1 = *(const short8*)(G_all + (size_t)j * SLOT + gb + 8);
          float a = 0.f;
#pragma unroll
          for (int i = 0; i < 8; ++i)
            a += gd16[i] * bf2f((u16)q0[i]) + gd16[8 + i] * bf2f((u16)q1[i]);
          gacc[j] = a;
        }
      }
      float vals[7] = {gacc[0], gacc[1], gacc[2], gacc[3], gacc[4], sd, sf};
#pragma unroll
      for (int i = 0; i < 7; ++i) {
        float v = vals[i];
#pragma unroll
        for (int off = 1; off < 64; off <<= 1) v += __shfl_xor(v, off);
        if (lane == 0) red[wid * 8 + i] = v;
      }
    }
    __syncthreads();
    if (tid < 7) {
      float s = 0.f;
#pragma unroll
      for (int w = 0; w < 16; ++w) s += red[w * 8 + tid];
      if (tid < 5)       gpart[(size_t)bid * 5 + tid] = s;
      else if (tid == 5) resp[bid * 2] = s;
      else               resp[bid * 2 + 1] = s;
    }
    gsync(cnt, gen);
    // ================= DEC: global res + per-image gram fold ====================
    if (tid < 64) {
      float sdv = 0.f, sfv = 0.f;
      for (int i = tid; i < NBLK; i += 64) { sdv += resp[2 * i]; sfv += resp[2 * i + 1]; }
#pragma unroll
      for (int off = 1; off < 64; off <<= 1) { sdv += __shfl_xor(sdv, off); sfv += __shfl_xor(sfv, off); }
      if (tid == 0) *res_s = sqrtf(sdv) / (1e-5f + sqrtf(sfv));
    }
    if (tid < 5) {
      float s = 0.f;
#pragma unroll
      for (int c = 0; c < 8; ++c) s += gpart[(size_t)((n << 3) + c) * 5 + tid];
      gram_s[slot * 5 + tid] = s;
      gram_s[tid * 5 + slot] = s;
    }
    __syncthreads();
    float res = *res_s;
    if ((e >= 2 && res < 1e-5f) || e == 49) break;   // identical data in every block
  }

  // ============ OUT: fnew regs -> NCHW via As bounce (2 channel halves) ========
  float* Asf = (float*)smem;
#pragma unroll
  for (int h = 0; h < 2; ++h) {
    __syncthreads();
    if ((wc >> 2) == h) {
#pragma unroll
      for (int m2 = 0; m2 < 4; ++m2)
#pragma unroll
        for (int rr = 0; rr < 4; ++rr) {
          int p = (wr << 6) + (m2 << 4) + (lhi << 2) + rr;
          Asf[p * 65 + (colc & 63)] = acc[m2][rr];
        }
    }
    __syncthreads();
    int c = tid >> 4, q = tid & 15;
    float* ob = out + (((size_t)(n << 7) + (h << 6) + c) << 10) + (y0 << 5) + (q << 3);
    f32x4 v0, v1;
#pragma unroll
    for (int i = 0; i < 4; ++i) {
      v0[i] = Asf[(q * 8 + i) * 65 + c];
      v1[i] = Asf[(q * 8 + 4 + i) * 65 + c];
    }
    *(f32x4*)ob = v0;
    *(f32x4*)(ob + 4) = v1;
  }
}

extern "C" void kernel_launch(void* const* d_in, const int* in_sizes, int n_in,
                              void* d_out, int out_size, void* d_ws, size_t ws_size,
                              hipStream_t stream) {
  const float* x    = (const float*)d_in[0];   // [32,128,32,32]
  const float* W    = (const float*)d_in[1];   // [128,128,3,3]
  const float* bias = (const float*)d_in[2];   // [128]
  const int*   mask = (const int*)d_in[3];     // [32,1,32,32]
  float* out = (float*)d_out;
  char* ws = (char*)d_ws;

  float*    Fh    = (float*)(ws + 0);              // 83,886,080
  u16*      G     = (u16*)(ws + 83886080);         // 41,943,040
  u16*      zm    = (u16*)(ws + 125829120);        // 8,388,608
  u16*      Wb    = (u16*)(ws + 134217728);        // 294,912
  float*    gpart = (float*)(ws + 134512640);      // 5,120
  float*    resp  = (float*)(ws + 134517760);      // 2,048
  unsigned* cnt   = (unsigned*)(ws + 134519808);
  unsigned* gen   = (unsigned*)(ws + 134519872);

  k_prepw<<<576, 256, 0, stream>>>(W, Wb, cnt, gen);
  k_prepx<<<2048, 256, 0, stream>>>(x, mask, zm);
  k_loop<<<NBLK, 1024, 0, stream>>>(zm, mask, Wb, bias, Fh, G, gpart, resp,
                                    out, cnt, gen);
  (void)in_sizes; (void)n_in; (void)out_size; (void)ws_size;
}

// Round 5
// 415.457 us; speedup vs baseline: 2.8630x; 2.8630x over previous
//
#include <hip/hip_runtime.h>

// MON forward-backward splitting via Anderson acceleration, MI355X/gfx950.
// R4: one kernel per iteration (launch boundary = grid sync; no atomics barrier).
//     Block = 4-row tile; FX computed redundantly for 6 halo'd rows and written
//     straight into the LDS conv tile (no global zm/xnew). z kept f32 in LDS.
//     res-gate + gram fold + 6x6 solve run redundantly per block at kernel head.

typedef unsigned short u16;
using short8 = __attribute__((ext_vector_type(8))) short;
using f32x4  = __attribute__((ext_vector_type(4))) float;

#define SLOT 4194304              // elements per history slot (32768 px * 128 ch)

struct Ctrl { int done; int last_slot; };

__device__ __forceinline__ u16 f2bf(float f) {
  unsigned u = __builtin_bit_cast(unsigned, f);
  unsigned r = (u + 0x7FFFu + ((u >> 16) & 1u)) >> 16;   // RNE, finite inputs
  return (u16)r;
}
__device__ __forceinline__ float bf2f(u16 h) {
  unsigned u = ((unsigned)h) << 16;
  return __builtin_bit_cast(float, u);
}

// ---------------- W[cout][cin][ky][kx] f32 -> Wb[o][cout][cin] bf16; ctrl init
__global__ void __launch_bounds__(256) k_prepw(const float* __restrict__ W,
    u16* __restrict__ Wb, Ctrl* ctrl) {
  if (blockIdx.x == 0 && threadIdx.x == 0) { ctrl->done = 0; ctrl->last_slot = 4; }
  int t = blockIdx.x * 256 + threadIdx.x;       // 9*128*128 threads
  int o = t >> 14;
  int rem = t & 16383;
  int cout = rem >> 7, cin = rem & 127;
  float v = W[(size_t)cout * 1152 + (size_t)cin * 9 + o];
  Wb[(size_t)o * 16384 + (size_t)cout * 128 + cin] = f2bf(v);
}

// ---------------- x NCHW f32 -> xsw bf16 swizzled NHWC
__global__ void __launch_bounds__(256) k_prepx(const float* __restrict__ x,
    const int* __restrict__ mask_, u16* __restrict__ xsw) {
  int t = blockIdx.x * 256 + threadIdx.x;       // 524288 threads
  int g = t >> 15, p = t & 32767;
  int nb = p >> 10, gp = p & 1023, px = p & 31;
  short8 xv;
#pragma unroll
  for (int u = 0; u < 8; ++u) {
    float v = x[(size_t)nb * 131072 + (size_t)(g * 8 + u) * 1024 + gp];
    xv[u] = (short)f2bf(v);
  }
  (void)mask_;
  *(short8*)(xsw + (size_t)p * 128 + (size_t)((g ^ (px & 7)) << 3)) = xv;
}

// ---------------- one Anderson iteration (eval e), fully fused ----------------
// 256 blocks x 1024 threads; block = 4 rows (128 px) of one image; 8 blocks/image.
// Phases: [done gate] [res gate e>=3] [gram fold e>=1] [solve e>=2] ->
//         FX (6 halo'd rows -> LDS tile + f32 zbuf) -> conv MFMA -> epilogue
//         (damp, softmax, Fh/G writes, gram+res partials).
__global__ void __launch_bounds__(1024) k_iter(
    const int e,
    const u16* __restrict__ xsw, const int* __restrict__ mask_,
    const u16* __restrict__ Wb, const float* __restrict__ bias,
    float* __restrict__ Fh, u16* __restrict__ G_all,
    float* __restrict__ gram, float* __restrict__ gpart,
    float* __restrict__ resp, Ctrl* __restrict__ ctrl)
{
  __shared__ char smem[129344];
  char*  As       = smem;                        // 6 rows * 34 cols * 256B = 52224
  float* zbuf     = (float*)(smem + 52224);      // 128 px * 132 f32 = 67584
  float* rowmax_s = (float*)(smem + 119808);     // [128][8] = 4096
  float* rowsum_s = (float*)(smem + 123904);     // 4096
  float* red      = (float*)(smem + 128000);     // 16 waves * 8 = 512
  float* alpha_s  = (float*)(smem + 128512);     // 5
  float* res_s    = (float*)(smem + 128544);     // 1
  int*   mk6      = (int*)(smem + 128560);       // 192

  if (ctrl->done) return;

  const int tid = threadIdx.x;
  const int wid = tid >> 6, lane = tid & 63;
  const int lhi = lane >> 4, llo = lane & 15;
  const int wr = wid >> 3, wc = wid & 7;
  const int bid = blockIdx.x;
  const int n = bid >> 3, y0 = (bid & 7) << 2;
  const int pixbase = (n << 10) + (y0 << 5);
  const int colc = (wc << 4) + llo;
  const int slot = e % 5;
  const int nact = e < 5 ? e : 5;

  // ---- res gate: reference's while-cond before body e uses res of eval e-1 ----
  if (e >= 3) {
    if (tid < 64) {
      float sd = 0.f, sf = 0.f;
      for (int i = tid; i < 256; i += 64) { sd += resp[2 * i]; sf += resp[2 * i + 1]; }
#pragma unroll
      for (int off = 1; off < 64; off <<= 1) { sd += __shfl_xor(sd, off); sf += __shfl_xor(sf, off); }
      if (tid == 0) res_s[0] = sqrtf(sd) / (1e-5f + sqrtf(sf));
    }
    __syncthreads();
    if (res_s[0] < 1e-5f) {                      // identical decision in every block
      if (tid == 0) { ctrl->done = 1; ctrl->last_slot = (e - 1) % 5; }
      return;
    }
  }

  // ---- mask stage (waves 0-2) + gram fold (wave 15), then solve ----
  if (tid < 192) {
    int gy = y0 - 1 + (tid >> 5);
    mk6[tid] = ((unsigned)gy < 32u) ? mask_[(n << 10) + (gy << 5) + (tid & 31)] : 0;
  }
  if (e >= 1 && tid >= 960 && tid < 965) {       // fold gram row/col for slot (e-1)%5
    int j = tid - 960;
    float s = 0.f;
#pragma unroll
    for (int c = 0; c < 8; ++c) s += gpart[(size_t)((n << 3) + c) * 5 + j];
    int sp = (e - 1) % 5;
    gram[n * 25 + sp * 5 + j] = s;               // all 8 blocks of image n write
    gram[n * 25 + j * 5 + sp] = s;               // identical values: benign
  }
  __syncthreads();
  if (e >= 2) {
    if (tid == 0) {                              // bordered 6x6 solve, f32 GE w/ pivot
      float A[6][7];
      for (int i = 0; i < 5; ++i)
        for (int j = 0; j < 5; ++j)
          A[i + 1][j + 1] = (i < nact && j < nact)
              ? gram[n * 25 + i * 5 + j] + ((i == j) ? 1e-4f : 0.f)
              : ((i == j) ? 1.f : 0.f);
      A[0][0] = 0.f;
      for (int j = 0; j < 5; ++j) { float aj = (j < nact) ? 1.f : 0.f; A[0][j + 1] = aj; A[j + 1][0] = aj; }
      A[0][6] = 1.f;
      for (int i = 1; i < 6; ++i) A[i][6] = 0.f;
      for (int c = 0; c < 6; ++c) {
        int p = c; float mx = fabsf(A[c][c]);
        for (int r = c + 1; r < 6; ++r) { float v = fabsf(A[r][c]); if (v > mx) { mx = v; p = r; } }
        if (p != c) for (int q = c; q < 7; ++q) { float tmp = A[c][q]; A[c][q] = A[p][q]; A[p][q] = tmp; }
        float piv = A[c][c];
        for (int r = c + 1; r < 6; ++r) {
          float fr = A[r][c] / piv;
          for (int q = c; q < 7; ++q) A[r][q] -= fr * A[c][q];
        }
      }
      float sol[6];
      for (int r = 5; r >= 0; --r) {
        float s = A[r][6];
        for (int q = r + 1; q < 6; ++q) s -= A[r][q] * sol[q];
        sol[r] = s / A[r][r];
      }
      for (int j = 0; j < 5; ++j) alpha_s[j] = sol[j + 1];
    }
  } else if (tid < 5) {
    alpha_s[tid] = (tid == 0) ? 1.f : 0.f;       // e==1: xnew = F0 (e==0 ignores)
  }
  __syncthreads();

  // ---- FX: z = sum_j alpha_j Fh_j for 6 halo'd rows -> LDS tile (+f32 zbuf) ----
  {
    const float a0 = alpha_s[0], a1 = alpha_s[1], a2 = alpha_s[2],
                a3 = alpha_s[3], a4 = alpha_s[4];
#pragma unroll
    for (int uu = 0; uu < 3; ++uu) {             // 3072 units = 6 rows*32 px*16 grp
      int unit = (uu << 10) + tid;
      int grp = unit & 15, px6 = unit >> 4;
      int row6 = px6 >> 5, px = px6 & 31;
      int gy = y0 - 1 + row6;
      char* dst = As + row6 * 8704 + ((px + 1) << 8) + ((grp ^ (px & 7)) << 4);
      short8 w = {0, 0, 0, 0, 0, 0, 0, 0};
      if ((unsigned)gy < 32u) {
        int gpix = (n << 10) + (gy << 5) + px;
        f32x4 va, vb;
        if (e == 0) {
          const f32x4 cz = {0.0078125f, 0.0078125f, 0.0078125f, 0.0078125f};
          va = cz; vb = cz;
        } else {
          const float* fb = Fh + (size_t)gpix * 128 + (grp << 3);
          va = a0 * *(const f32x4*)fb;
          vb = a0 * *(const f32x4*)(fb + 4);
          if (nact > 1) { va += a1 * *(const f32x4*)(fb + SLOT);     vb += a1 * *(const f32x4*)(fb + SLOT + 4); }
          if (nact > 2) { va += a2 * *(const f32x4*)(fb + 2 * SLOT); vb += a2 * *(const f32x4*)(fb + 2 * SLOT + 4); }
          if (nact > 3) { va += a3 * *(const f32x4*)(fb + 3 * SLOT); vb += a3 * *(const f32x4*)(fb + 3 * SLOT + 4); }
          if (nact > 4) { va += a4 * *(const f32x4*)(fb + 4 * SLOT); vb += a4 * *(const f32x4*)(fb + 4 * SLOT + 4); }
        }
        if (mk6[px6]) {
          w = *(const short8*)(xsw + (size_t)gpix * 128 + ((grp ^ (px & 7)) << 3));
        } else {
#pragma unroll
          for (int i = 0; i < 4; ++i) { w[i] = (short)f2bf(va[i]); w[4 + i] = (short)f2bf(vb[i]); }
        }
        if (row6 >= 1 && row6 <= 4) {            // own rows: keep f32 z for damping/G
          float* zb = zbuf + (px6 - 32) * 132 + (grp << 3);
          *(f32x4*)zb = va;
          *(f32x4*)(zb + 4) = vb;
        }
      }
      *(short8*)dst = w;
    }
    if (tid < 192) {                             // zero pads: cols 0 and 33, 6 rows
      int r = tid >> 5, cc = tid & 31;
      int col = (cc < 16) ? 0 : 33, gc = cc & 15;
      f32x4 zz = {0.f, 0.f, 0.f, 0.f};
      *(f32x4*)(As + r * 8704 + (col << 8) + (gc << 4)) = zz;
    }
  }
  __syncthreads();

  // ---- CONV: 144 MFMAs/wave off the LDS tile; B frags from global (L2-hot) ----
  f32x4 acc[4];
  {
    const f32x4 z4 = {0.f, 0.f, 0.f, 0.f};
    acc[0] = z4; acc[1] = z4; acc[2] = z4; acc[3] = z4;
  }
#pragma unroll
  for (int o = 0; o < 9; ++o) {
    const int dy = o / 3, dx = o % 3;
    short8 bfr[4];
#pragma unroll
    for (int kk = 0; kk < 4; ++kk)
      bfr[kk] = *(const short8*)(Wb + o * 16384 + colc * 128 + ((kk << 2) + lhi) * 8);
#pragma unroll
    for (int kk = 0; kk < 4; ++kk) {
      const int kg = (kk << 2) + lhi;
#pragma unroll
      for (int m2 = 0; m2 < 4; ++m2) {
        int p = (wr << 6) + (m2 << 4) + llo;
        int r = (p >> 5) + dy, cl = (p & 31) + dx;
        int sg = kg ^ ((cl - 1) & 7);
        short8 af = *(const short8*)(As + r * 8704 + (cl << 8) + (sg << 4));
        acc[m2] = __builtin_amdgcn_mfma_f32_16x16x32_bf16(af, bfr[kk], acc[m2], 0, 0, 0);
      }
    }
  }

  // ---- epilogue: damp, channel-softmax(128), fnew, G, gram/res partials ----
  const float bc = bias[colc];
  float zr[16];
#pragma unroll
  for (int m2 = 0; m2 < 4; ++m2)
#pragma unroll
    for (int rr = 0; rr < 4; ++rr) {
      int p = (wr << 6) + (m2 << 4) + (lhi << 2) + rr;
      float z = zbuf[p * 132 + colc];
      zr[m2 * 4 + rr] = z;
      acc[m2][rr] = 0.1f * z + 0.9f * (acc[m2][rr] + bc);
    }
#pragma unroll
  for (int m2 = 0; m2 < 4; ++m2)
#pragma unroll
    for (int rr = 0; rr < 4; ++rr) {
      float v = acc[m2][rr];
      v = fmaxf(v, __shfl_xor(v, 1)); v = fmaxf(v, __shfl_xor(v, 2));
      v = fmaxf(v, __shfl_xor(v, 4)); v = fmaxf(v, __shfl_xor(v, 8));
      if (llo == 0) rowmax_s[((wr << 6) + (m2 << 4) + (lhi << 2) + rr) * 8 + wc] = v;
    }
  __syncthreads();
#pragma unroll
  for (int m2 = 0; m2 < 4; ++m2)
#pragma unroll
    for (int rr = 0; rr < 4; ++rr) {
      int p = (wr << 6) + (m2 << 4) + (lhi << 2) + rr;
      f32x4 m0 = *(const f32x4*)&rowmax_s[p * 8];
      f32x4 m1 = *(const f32x4*)&rowmax_s[p * 8 + 4];
      float M = fmaxf(fmaxf(fmaxf(m0[0], m0[1]), fmaxf(m0[2], m0[3])),
                      fmaxf(fmaxf(m1[0], m1[1]), fmaxf(m1[2], m1[3])));
      float ev = __expf(acc[m2][rr] - M);
      acc[m2][rr] = ev;
      float s = ev;
      s += __shfl_xor(s, 1); s += __shfl_xor(s, 2);
      s += __shfl_xor(s, 4); s += __shfl_xor(s, 8);
      if (llo == 0) rowsum_s[p * 8 + wc] = s;
    }
  __syncthreads();

  float sd = 0.f, sf = 0.f;
  float gd16[16];
#pragma unroll
  for (int m2 = 0; m2 < 4; ++m2)
#pragma unroll
    for (int rr = 0; rr < 4; ++rr) {
      int p = (wr << 6) + (m2 << 4) + (lhi << 2) + rr;
      f32x4 s0 = *(const f32x4*)&rowsum_s[p * 8];
      f32x4 s1 = *(const f32x4*)&rowsum_s[p * 8 + 4];
      float S = s0[0] + s0[1] + s0[2] + s0[3] + s1[0] + s1[1] + s1[2] + s1[3];
      float fnew = acc[m2][rr] * (1.0f / S);
      Fh[(size_t)slot * SLOT + (size_t)(pixbase + p) * 128 + colc] = fnew;
      float gd = fnew - zr[m2 * 4 + rr];
      gd16[m2 * 4 + rr] = gd;
      sd += gd * gd; sf += fnew * fnew;
    }
  {
    short8 h0, h1;
#pragma unroll
    for (int i = 0; i < 8; ++i) { h0[i] = (short)f2bf(gd16[i]); h1[i] = (short)f2bf(gd16[8 + i]); }
    size_t gb = (size_t)bid * 16384 + (size_t)tid * 16;   // packed-linear G layout
    u16* Gs = G_all + (size_t)slot * SLOT;
    *(short8*)(Gs + gb) = h0;
    *(short8*)(Gs + gb + 8) = h1;
    const int jmax = e < 4 ? e : 4;              // valid slots this iteration
    float gacc[5];
#pragma unroll
    for (int j = 0; j < 5; ++j) {
      if (j > jmax) { gacc[j] = 0.f; continue; }
      if (j == slot) {
        float a = 0.f;
#pragma unroll
        for (int i = 0; i < 16; ++i) a += gd16[i] * gd16[i];
        gacc[j] = a;
      } else {
        short8 q0 = *(const short8*)(G_all + (size_t)j * SLOT + gb);
        short8 q1 = *(const short8*)(G_all + (size_t)j * SLOT + gb + 8);
        float a = 0.f;
#pragma unroll
        for (int i = 0; i < 8; ++i)
          a += gd16[i] * bf2f((u16)q0[i]) + gd16[8 + i] * bf2f((u16)q1[i]);
        gacc[j] = a;
      }
    }
    float vals[7] = {gacc[0], gacc[1], gacc[2], gacc[3], gacc[4], sd, sf};
#pragma unroll
    for (int i = 0; i < 7; ++i) {
      float v = vals[i];
#pragma unroll
      for (int off = 1; off < 64; off <<= 1) v += __shfl_xor(v, off);
      if (lane == 0) red[wid * 8 + i] = v;
    }
  }
  __syncthreads();
  if (tid < 7) {
    float s = 0.f;
#pragma unroll
    for (int w = 0; w < 16; ++w) s += red[w * 8 + tid];
    if (tid < 5)       gpart[(size_t)bid * 5 + tid] = s;
    else if (tid == 5) resp[bid * 2] = s;
    else               resp[bid * 2 + 1] = s;
  }
}

// ---------------- final: Fh[last_slot] NHWC f32 -> d_out NCHW f32
__global__ void __launch_bounds__(256) k_out(const float* __restrict__ Fh,
    const Ctrl* __restrict__ ctrl, float* __restrict__ out)
{
  __shared__ float T[64][129];
  int slot = ctrl->last_slot;
  const float* src = Fh + (size_t)slot * SLOT;
  int bid = blockIdx.x;                          // 512 = 32 batches * 16 segments
  int nb = bid >> 4, seg = bid & 15;
  int pixbase = (nb << 10) + (seg << 6);
  for (int it = 0; it < 32; ++it) {
    int idx = it * 256 + threadIdx.x;
    int pix = idx >> 7, c = idx & 127;
    T[pix][c] = src[(size_t)(pixbase + pix) * 128 + c];
  }
  __syncthreads();
  for (int it = 0; it < 32; ++it) {
    int idx = it * 256 + threadIdx.x;
    int c = idx >> 6, pix = idx & 63;
    out[(size_t)((nb << 7) + c) * 1024 + (seg << 6) + pix] = T[pix][c];
  }
}

extern "C" void kernel_launch(void* const* d_in, const int* in_sizes, int n_in,
                              void* d_out, int out_size, void* d_ws, size_t ws_size,
                              hipStream_t stream) {
  const float* x    = (const float*)d_in[0];   // [32,128,32,32]
  const float* W    = (const float*)d_in[1];   // [128,128,3,3]
  const float* bias = (const float*)d_in[2];   // [128]
  const int*   mask = (const int*)d_in[3];     // [32,1,32,32]
  float* out = (float*)d_out;
  char* ws = (char*)d_ws;

  float* Fh    = (float*)(ws + 0);             // 83,886,080
  u16*   G     = (u16*)(ws + 83886080);        // 41,943,040 (packed-linear)
  u16*   xsw   = (u16*)(ws + 125829120);       // 8,388,608
  u16*   Wb    = (u16*)(ws + 134217728);       // 294,912
  float* gram  = (float*)(ws + 134512640);     // 3,200
  float* gpart = (float*)(ws + 134515840);     // 5,120
  float* resp  = (float*)(ws + 134520960);     // 2,048
  Ctrl*  ctrl  = (Ctrl*)(ws + 134523008);

  k_prepw<<<576, 256, 0, stream>>>(W, Wb, ctrl);
  k_prepx<<<2048, 256, 0, stream>>>(x, mask, xsw);
  for (int e = 0; e < 50; ++e)
    k_iter<<<256, 1024, 0, stream>>>(e, xsw, mask, Wb, bias,
                                     Fh, G, gram, gpart, resp, ctrl);
  k_out<<<512, 256, 0, stream>>>(Fh, ctrl, out);
  (void)in_sizes; (void)n_in; (void)out_size; (void)ws_size;
}